// Round 8
// baseline (292.153 us; speedup 1.0000x reference)
//
#include <hip/hip_runtime.h>
#include <hip/hip_bf16.h>

// B=32768, D=1024, U=1024, R=4, H=16, ND=11
// Fully fused: out = relu(x@kernel + bias_tot + dom(x_row)@Beff); dom computed in-loop
// from the same LDS A-tile (dA = x@Acat accumulated over K via extra MFMA).

typedef float f32x4 __attribute__((ext_vector_type(4)));
typedef short s16x8 __attribute__((ext_vector_type(8)));
typedef unsigned int u32x4 __attribute__((ext_vector_type(4)));

// ws layout (bytes)
#define WS_BEFF   524288u    // 4*1024 f32
#define WS_BIAS   540672u    // 1024 f32
#define WS_G      544768u    // 16 f32
#define WS_M      545024u    // 16 f32
#define WS_ACATT  545280u    // 64*1024 bf16
#define WS_KB     679936u    // 1024*1024 bf16 (ends 2777088)

__device__ __forceinline__ unsigned short f2bf(float f) {
  unsigned int u = __builtin_bit_cast(unsigned int, f);
  u += 0x7fffu + ((u >> 16) & 1u);   // round-to-nearest-even
  return (unsigned short)(u >> 16);
}
__device__ __forceinline__ unsigned int f2bf2(float a, float b) {
  return (unsigned int)f2bf(a) | ((unsigned int)f2bf(b) << 16);
}

__device__ __forceinline__ void gload_lds16(const void* g, void* l) {
  __builtin_amdgcn_global_load_lds((const __attribute__((address_space(1))) void*)g,
                                   (__attribute__((address_space(3))) void*)l, 16, 0, 0);
}

// ---------------- prep1: w, G, M, bias_tot, Beff ----------------
__global__ void prep1(const float* __restrict__ factor, const float* __restrict__ WQ,
                      const float* __restrict__ WK, const float* __restrict__ WV,
                      const float* __restrict__ linear, const float* __restrict__ bias,
                      const float* __restrict__ domain_bias, const float* __restrict__ b_kernel,
                      const int* __restrict__ dom_ind, float* __restrict__ ws_f) {
  __shared__ float wsm[10];
  const int t = threadIdx.x;
  float* G    = ws_f + (WS_G >> 2);
  float* M    = ws_f + (WS_M >> 2);
  float* beff = ws_f + (WS_BEFF >> 2);
  float* btot = ws_f + (WS_BIAS >> 2);
  if (t == 0) {
    float f[11], mx = -1e30f;
    for (int i = 0; i < 11; i++) { f[i] = factor[i]; mx = fmaxf(mx, f[i]); }
    float s = 0.f;
    for (int i = 0; i < 11; i++) { f[i] = expf(f[i] - mx); s += f[i]; }
    float inv = 1.0f / s;
    for (int i = 0; i < 10; i++) wsm[i] = f[i + 1] * inv;
  }
  if (t < 16) {
    int r = t >> 2, c = t & 3;
    float g = 0.f, m = 0.f;
    for (int h = 0; h < 16; h++) {
      g += WQ[r * 16 + h] * WK[c * 16 + h];
      m += WV[r * 16 + h] * linear[h * 4 + c];
    }
    G[t] = 0.25f * g;   // scale = 1/sqrt(H) = 0.25
    M[t] = m;
  }
  __syncthreads();
  const int idx = dom_ind[0];
  for (int u = t; u < 1024; u += 256) btot[u] = bias[u] + domain_bias[idx * 1024 + u];
  for (int i = t; i < 4096; i += 256) {
    int r = i >> 10, u = i & 1023;
    float s = 0.f;
    for (int n = 0; n < 10; n++) s += wsm[n] * b_kernel[(1 + n) * 4096 + r * 1024 + u];
    beff[i] = s;
  }
}

// ---------------- prep2: Acatt[c][d] bf16, c=n*4+r (transposed, zero-padded to 64) ----------------
__global__ void prep2(const float* __restrict__ a_kernel, unsigned short* __restrict__ acatt) {
  const int i = blockIdx.x * 256 + threadIdx.x;  // 65536
  const int c = i >> 10, d = i & 1023;
  float v = 0.0f;
  if (c < 40) v = a_kernel[(1 + (c >> 2)) * 4096 + d * 4 + (c & 3)];
  acatt[i] = f2bf(v);
}

// ---------------- transK: kb[n][k] = bf16(kernel[k][n]) ----------------
__global__ void transK(const float* __restrict__ kern, unsigned short* __restrict__ kb) {
  __shared__ float tile[32][33];
  const int t = threadIdx.x;
  const int kt = blockIdx.x >> 5, nt = blockIdx.x & 31;
  const int k0 = kt << 5, n0 = nt << 5;
  const int row = t >> 5, col = t & 31;
#pragma unroll
  for (int i = 0; i < 4; i++)
    tile[row + i * 8][col] = kern[(k0 + row + i * 8) * 1024 + n0 + col];
  __syncthreads();
  const int nrow = t >> 3, kq = t & 7;
  uint2 pv;
  pv.x = f2bf2(tile[kq * 4 + 0][nrow], tile[kq * 4 + 1][nrow]);
  pv.y = f2bf2(tile[kq * 4 + 2][nrow], tile[kq * 4 + 3][nrow]);
  *reinterpret_cast<uint2*>(&kb[(n0 + nrow) * 1024 + k0 + kq * 4]) = pv;
}

// ---------------- fusedGEMM: 128x128xBK64, m97 structure + in-loop dA + attention tail ----------------
__launch_bounds__(256, 3)
__global__ void fusedGEMM(const float* __restrict__ x, const unsigned short* __restrict__ kb,
                          const unsigned short* __restrict__ acatt,
                          const float* __restrict__ ws_f, float* __restrict__ out) {
  __shared__ __align__(16) char smem[32768];
  unsigned short* As = (unsigned short*)smem;            // 128x64 bf16 swizzled (16 KB)
  unsigned short* Bs = (unsigned short*)(smem + 16384);  // 128x64 bf16 swizzled (16 KB)
  const int t = threadIdx.x;
  const int w = t >> 6, l = t & 63;
  // XCD-locality swizzle: xcd = b&7 owns 32 contiguous row-panels, col-tiles inner.
  const int b = blockIdx.x;
  const int xcd = b & 7, i6 = b >> 3;
  const int bm = (xcd << 5) + (i6 >> 3), bn = i6 & 7;
  const int rows0 = bm << 7, cols0 = bn << 7;
  const int wr = w >> 1, wc = w & 1;
  const int lr = l & 15, kg = l >> 4;
  const float* beff = ws_f + (WS_BEFF >> 2);
  const float* btot = ws_f + (WS_BIAS >> 2);
  const f32x4 zero4 = {0.f, 0.f, 0.f, 0.f};
  f32x4 acc[4][4];
#pragma unroll
  for (int i = 0; i < 4; i++)
#pragma unroll
    for (int j = 0; j < 4; j++) acc[i][j] = zero4;
  f32x4 accd[2][3];   // dA accumulator: wave w owns rows w*32..+32 (mf2 in {0,1})
#pragma unroll
  for (int i = 0; i < 2; i++)
#pragma unroll
    for (int j = 0; j < 3; j++) accd[i][j] = zero4;

#pragma unroll 1
  for (int kc = 0; kc < 16; kc++) {
    if (kc) __syncthreads();
    // stage B tile via source-pre-swizzled global_load_lds
#pragma unroll
    for (int i = 0; i < 4; i++) {
      int segid = i * 256 + t;
      int c = segid >> 3, ks = segid & 7;
      gload_lds16(kb + (cols0 + c) * 1024 + (kc << 6) + ((ks ^ (c & 7)) << 3), Bs + segid * 8);
    }
    // stage A tile: x f32 -> bf16 reg-staged, swizzled ds_write
#pragma unroll
    for (int i = 0; i < 4; i++) {
      int segid = i * 256 + t;
      int row = segid >> 3, ks = segid & 7;
      const float* gp = x + (size_t)(rows0 + row) * 1024 + (kc << 6) + (ks << 3);
      f32x4 v0 = *reinterpret_cast<const f32x4*>(gp);
      f32x4 v1 = *reinterpret_cast<const f32x4*>(gp + 4);
      u32x4 o = { f2bf2(v0[0], v0[1]), f2bf2(v0[2], v0[3]),
                  f2bf2(v1[0], v1[1]), f2bf2(v1[2], v1[3]) };
      *reinterpret_cast<u32x4*>(As + row * 64 + ((ks ^ (row & 7)) << 3)) = o;
    }
    // dA B-fragments from L2-resident acatt (issue early; both kh halves)
    s16x8 bd[2][3];
#pragma unroll
    for (int kh = 0; kh < 2; kh++)
#pragma unroll
      for (int nf = 0; nf < 3; nf++)
        bd[kh][nf] = *reinterpret_cast<const s16x8*>(
            acatt + ((nf << 4) + lr) * 1024 + (kc << 6) + (kh << 5) + (kg << 3));
    __syncthreads();
    // compute
#pragma unroll
    for (int kh = 0; kh < 2; kh++) {
      const int cp = (kh << 2) + kg;
      s16x8 av[4], bv[4];
#pragma unroll
      for (int mf = 0; mf < 4; mf++) {
        int arow = (wr << 6) + (mf << 4) + lr;
        av[mf] = *reinterpret_cast<const s16x8*>(As + arow * 64 + ((cp ^ (arow & 7)) << 3));
      }
#pragma unroll
      for (int nf = 0; nf < 4; nf++) {
        int brow = (wc << 6) + (nf << 4) + lr;
        bv[nf] = *reinterpret_cast<const s16x8*>(Bs + brow * 64 + ((cp ^ (brow & 7)) << 3));
      }
#pragma unroll
      for (int mf = 0; mf < 4; mf++)
#pragma unroll
        for (int nf = 0; nf < 4; nf++)
          acc[mf][nf] = __builtin_amdgcn_mfma_f32_16x16x32_bf16(av[mf], bv[nf], acc[mf][nf], 0, 0, 0);
      // dA: rows w*32 + mf2*16
#pragma unroll
      for (int mf2 = 0; mf2 < 2; mf2++) {
        int arow2 = (w << 5) + (mf2 << 4) + lr;
        s16x8 av2 = *reinterpret_cast<const s16x8*>(As + arow2 * 64 + ((cp ^ (arow2 & 7)) << 3));
#pragma unroll
        for (int nf = 0; nf < 3; nf++)
          accd[mf2][nf] = __builtin_amdgcn_mfma_f32_16x16x32_bf16(av2, bd[kh][nf], accd[mf2][nf], 0, 0, 0);
      }
    }
  }

  // ---- tail: dA -> LDS (overlaying As/Bs), attention per row, dom in LDS ----
  __syncthreads();
  float (*dAs)[41] = (float(*)[41])smem;                 // 128 x 41 f32 = 20992 B
  float (*domL)[4] = (float(*)[4])(smem + 20992);        // 128 x 4  f32 = 2048 B
#pragma unroll
  for (int mf2 = 0; mf2 < 2; mf2++)
#pragma unroll
    for (int nf = 0; nf < 3; nf++) {
      const int col = (nf << 4) + lr;
      if (col < 40) {
#pragma unroll
        for (int j = 0; j < 4; j++)
          dAs[(w << 5) + (mf2 << 4) + (kg << 2) + j][col] = accd[mf2][nf][j];
      }
    }
  __syncthreads();
  if (t < 128) {
    const int row = t;
    const float* Gp = ws_f + (WS_G >> 2);
    const float* Mp = ws_f + (WS_M >> 2);
    float Gv[16];
#pragma unroll
    for (int i = 0; i < 16; i++) Gv[i] = Gp[i];
    float tm[10][4];
#pragma unroll
    for (int m = 0; m < 10; m++) {
      float d0 = dAs[row][(m << 2) + 0], d1 = dAs[row][(m << 2) + 1];
      float d2 = dAs[row][(m << 2) + 2], d3 = dAs[row][(m << 2) + 3];
#pragma unroll
      for (int r = 0; r < 4; r++)
        tm[m][r] = Gv[(r << 2) + 0] * d0 + Gv[(r << 2) + 1] * d1
                 + Gv[(r << 2) + 2] * d2 + Gv[(r << 2) + 3] * d3;
    }
    float cm[10];
#pragma unroll
    for (int m = 0; m < 10; m++) cm[m] = 0.f;
#pragma unroll
    for (int n = 0; n < 10; n++) {
      float d0 = dAs[row][(n << 2) + 0], d1 = dAs[row][(n << 2) + 1];
      float d2 = dAs[row][(n << 2) + 2], d3 = dAs[row][(n << 2) + 3];
      float sv[10]; float mx = -1e30f;
#pragma unroll
      for (int m = 0; m < 10; m++) {
        float s = d0 * tm[m][0] + d1 * tm[m][1] + d2 * tm[m][2] + d3 * tm[m][3];
        sv[m] = s; mx = fmaxf(mx, s);
      }
      float ssum = 0.f;
#pragma unroll
      for (int m = 0; m < 10; m++) { float e = expf(sv[m] - mx); sv[m] = e; ssum += e; }
      float inv = 1.0f / ssum;
#pragma unroll
      for (int m = 0; m < 10; m++) cm[m] += sv[m] * inv;
    }
    float u0 = 0.f, u1 = 0.f, u2 = 0.f, u3 = 0.f;
#pragma unroll
    for (int m = 0; m < 10; m++) {
      u0 += cm[m] * dAs[row][(m << 2) + 0];
      u1 += cm[m] * dAs[row][(m << 2) + 1];
      u2 += cm[m] * dAs[row][(m << 2) + 2];
      u3 += cm[m] * dAs[row][(m << 2) + 3];
    }
#pragma unroll
    for (int rp = 0; rp < 4; rp++)
      domL[row][rp] = u0 * Mp[rp] + u1 * Mp[4 + rp] + u2 * Mp[8 + rp] + u3 * Mp[12 + rp];
  }
  __syncthreads();

  // ---- epilogue: + bias_tot + dom@Beff, relu ----
  float bcv[4], bev[4][4];
#pragma unroll
  for (int nf = 0; nf < 4; nf++) {
    int col = cols0 + (wc << 6) + (nf << 4) + lr;
    bcv[nf] = btot[col];
#pragma unroll
    for (int r = 0; r < 4; r++) bev[nf][r] = beff[r * 1024 + col];
  }
#pragma unroll
  for (int mf = 0; mf < 4; mf++) {
    const int lbase = (wr << 6) + (mf << 4) + (kg << 2);
    f32x4 dm[4];
#pragma unroll
    for (int j = 0; j < 4; j++)
      dm[j] = *reinterpret_cast<const f32x4*>(domL[lbase + j]);
#pragma unroll
    for (int nf = 0; nf < 4; nf++) {
      const int col = cols0 + (wc << 6) + (nf << 4) + lr;
#pragma unroll
      for (int j = 0; j < 4; j++) {
        float v = acc[mf][nf][j] + bcv[nf]
                + dm[j][0] * bev[nf][0] + dm[j][1] * bev[nf][1]
                + dm[j][2] * bev[nf][2] + dm[j][3] * bev[nf][3];
        out[(size_t)(rows0 + lbase + j) * 1024 + col] = fmaxf(v, 0.f);
      }
    }
  }
}

extern "C" void kernel_launch(void* const* d_in, const int* in_sizes, int n_in,
                              void* d_out, int out_size, void* d_ws, size_t ws_size,
                              hipStream_t stream) {
  (void)in_sizes; (void)n_in; (void)out_size; (void)ws_size;
  const float* x           = (const float*)d_in[0];
  const int*   dom_ind     = (const int*)d_in[1];
  const float* kern        = (const float*)d_in[2];
  const float* bias        = (const float*)d_in[3];
  const float* a_kernel    = (const float*)d_in[4];
  const float* b_kernel    = (const float*)d_in[5];
  const float* domain_bias = (const float*)d_in[6];
  const float* WQ          = (const float*)d_in[7];
  const float* WK          = (const float*)d_in[8];
  const float* WV          = (const float*)d_in[9];
  const float* linear      = (const float*)d_in[10];
  const float* factor      = (const float*)d_in[11];
  float* out = (float*)d_out;
  char* ws = (char*)d_ws;
  float* ws_f = (float*)ws;
  unsigned short* acatt = (unsigned short*)(ws + WS_ACATT);
  unsigned short* kb    = (unsigned short*)(ws + WS_KB);

  prep1<<<1, 256, 0, stream>>>(factor, WQ, WK, WV, linear, bias, domain_bias, b_kernel, dom_ind, ws_f);
  prep2<<<256, 256, 0, stream>>>(a_kernel, acatt);
  transK<<<1024, 256, 0, stream>>>(kern, kb);
  fusedGEMM<<<2048, 256, 0, stream>>>(x, kb, acatt, ws_f, out);
}

// Round 9
// 222.173 us; speedup vs baseline: 1.3150x; 1.3150x over previous
//
#include <hip/hip_runtime.h>
#include <hip/hip_bf16.h>

// B=32768, D=1024, U=1024, R=4, H=16, ND=11
// Fully fused: out = relu(x@kernel + bias_tot + dom(x_row)@Beff); dom computed in-loop
// from the same LDS A-tile (dA = x@Acat accumulated over K via extra MFMA).

typedef float f32x4 __attribute__((ext_vector_type(4)));
typedef short s16x8 __attribute__((ext_vector_type(8)));
typedef unsigned int u32x4 __attribute__((ext_vector_type(4)));

// ws layout (bytes)
#define WS_BEFF   524288u    // 4*1024 f32
#define WS_BIAS   540672u    // 1024 f32
#define WS_G      544768u    // 16 f32
#define WS_M      545024u    // 16 f32
#define WS_ACATT  545280u    // 64*1024 bf16
#define WS_KB     679936u    // 1024*1024 bf16 (ends 2777088)

__device__ __forceinline__ unsigned short f2bf(float f) {
  unsigned int u = __builtin_bit_cast(unsigned int, f);
  u += 0x7fffu + ((u >> 16) & 1u);   // round-to-nearest-even
  return (unsigned short)(u >> 16);
}
__device__ __forceinline__ unsigned int f2bf2(float a, float b) {
  return (unsigned int)f2bf(a) | ((unsigned int)f2bf(b) << 16);
}

__device__ __forceinline__ void gload_lds16(const void* g, void* l) {
  __builtin_amdgcn_global_load_lds((const __attribute__((address_space(1))) void*)g,
                                   (__attribute__((address_space(3))) void*)l, 16, 0, 0);
}

// ---------------- prep1: w, G, M, bias_tot, Beff ----------------
__global__ void prep1(const float* __restrict__ factor, const float* __restrict__ WQ,
                      const float* __restrict__ WK, const float* __restrict__ WV,
                      const float* __restrict__ linear, const float* __restrict__ bias,
                      const float* __restrict__ domain_bias, const float* __restrict__ b_kernel,
                      const int* __restrict__ dom_ind, float* __restrict__ ws_f) {
  __shared__ float wsm[10];
  const int t = threadIdx.x;
  float* G    = ws_f + (WS_G >> 2);
  float* M    = ws_f + (WS_M >> 2);
  float* beff = ws_f + (WS_BEFF >> 2);
  float* btot = ws_f + (WS_BIAS >> 2);
  if (t == 0) {
    float f[11], mx = -1e30f;
    for (int i = 0; i < 11; i++) { f[i] = factor[i]; mx = fmaxf(mx, f[i]); }
    float s = 0.f;
    for (int i = 0; i < 11; i++) { f[i] = expf(f[i] - mx); s += f[i]; }
    float inv = 1.0f / s;
    for (int i = 0; i < 10; i++) wsm[i] = f[i + 1] * inv;
  }
  if (t < 16) {
    int r = t >> 2, c = t & 3;
    float g = 0.f, m = 0.f;
    for (int h = 0; h < 16; h++) {
      g += WQ[r * 16 + h] * WK[c * 16 + h];
      m += WV[r * 16 + h] * linear[h * 4 + c];
    }
    G[t] = 0.25f * g;   // scale = 1/sqrt(H) = 0.25
    M[t] = m;
  }
  __syncthreads();
  const int idx = dom_ind[0];
  for (int u = t; u < 1024; u += 256) btot[u] = bias[u] + domain_bias[idx * 1024 + u];
  for (int i = t; i < 4096; i += 256) {
    int r = i >> 10, u = i & 1023;
    float s = 0.f;
    for (int n = 0; n < 10; n++) s += wsm[n] * b_kernel[(1 + n) * 4096 + r * 1024 + u];
    beff[i] = s;
  }
}

// ---------------- prep2: Acatt[c][d] bf16, c=n*4+r (transposed, zero-padded to 64) ----------------
__global__ void prep2(const float* __restrict__ a_kernel, unsigned short* __restrict__ acatt) {
  const int i = blockIdx.x * 256 + threadIdx.x;  // 65536
  const int c = i >> 10, d = i & 1023;
  float v = 0.0f;
  if (c < 40) v = a_kernel[(1 + (c >> 2)) * 4096 + d * 4 + (c & 3)];
  acatt[i] = f2bf(v);
}

// ---------------- transK: kb[n][k] = bf16(kernel[k][n]) ----------------
__global__ void transK(const float* __restrict__ kern, unsigned short* __restrict__ kb) {
  __shared__ float tile[32][33];
  const int t = threadIdx.x;
  const int kt = blockIdx.x >> 5, nt = blockIdx.x & 31;
  const int k0 = kt << 5, n0 = nt << 5;
  const int row = t >> 5, col = t & 31;
#pragma unroll
  for (int i = 0; i < 4; i++)
    tile[row + i * 8][col] = kern[(k0 + row + i * 8) * 1024 + n0 + col];
  __syncthreads();
  const int nrow = t >> 3, kq = t & 7;
  uint2 pv;
  pv.x = f2bf2(tile[kq * 4 + 0][nrow], tile[kq * 4 + 1][nrow]);
  pv.y = f2bf2(tile[kq * 4 + 2][nrow], tile[kq * 4 + 3][nrow]);
  *reinterpret_cast<uint2*>(&kb[(n0 + nrow) * 1024 + k0 + kq * 4]) = pv;
}

// ---------------- fusedGEMM: 128x128xBK64, m97 structure + in-loop dA + attention tail ----------------
// __launch_bounds__(256,2): 256-reg/wave budget. acc(64 AGPR)+accd(24 AGPR)+~115 VGPR fits —
// (256,3) capped the unified file at 170 and spilled accumulators to scratch (round-8: +200MB writes).
__launch_bounds__(256, 2)
__global__ void fusedGEMM(const float* __restrict__ x, const unsigned short* __restrict__ kb,
                          const unsigned short* __restrict__ acatt,
                          const float* __restrict__ ws_f, float* __restrict__ out) {
  __shared__ __align__(16) char smem[32768];
  unsigned short* As = (unsigned short*)smem;            // 128x64 bf16 swizzled (16 KB)
  unsigned short* Bs = (unsigned short*)(smem + 16384);  // 128x64 bf16 swizzled (16 KB)
  const int t = threadIdx.x;
  const int w = t >> 6, l = t & 63;
  // XCD-locality swizzle: xcd = b&7 owns 32 contiguous row-panels, col-tiles inner.
  const int b = blockIdx.x;
  const int xcd = b & 7, i6 = b >> 3;
  const int bm = (xcd << 5) + (i6 >> 3), bn = i6 & 7;
  const int rows0 = bm << 7, cols0 = bn << 7;
  const int wr = w >> 1, wc = w & 1;
  const int lr = l & 15, kg = l >> 4;
  const float* beff = ws_f + (WS_BEFF >> 2);
  const float* btot = ws_f + (WS_BIAS >> 2);
  const f32x4 zero4 = {0.f, 0.f, 0.f, 0.f};
  f32x4 acc[4][4];
#pragma unroll
  for (int i = 0; i < 4; i++)
#pragma unroll
    for (int j = 0; j < 4; j++) acc[i][j] = zero4;
  f32x4 accd[2][3];   // dA accumulator: wave w owns rows w*32..+32 (mf2 in {0,1})
#pragma unroll
  for (int i = 0; i < 2; i++)
#pragma unroll
    for (int j = 0; j < 3; j++) accd[i][j] = zero4;

#pragma unroll 1
  for (int kc = 0; kc < 16; kc++) {
    if (kc) __syncthreads();
    // stage B tile via source-pre-swizzled global_load_lds
#pragma unroll
    for (int i = 0; i < 4; i++) {
      int segid = i * 256 + t;
      int c = segid >> 3, ks = segid & 7;
      gload_lds16(kb + (cols0 + c) * 1024 + (kc << 6) + ((ks ^ (c & 7)) << 3), Bs + segid * 8);
    }
    // stage A tile: x f32 -> bf16 reg-staged, swizzled ds_write
#pragma unroll
    for (int i = 0; i < 4; i++) {
      int segid = i * 256 + t;
      int row = segid >> 3, ks = segid & 7;
      const float* gp = x + (size_t)(rows0 + row) * 1024 + (kc << 6) + (ks << 3);
      f32x4 v0 = *reinterpret_cast<const f32x4*>(gp);
      f32x4 v1 = *reinterpret_cast<const f32x4*>(gp + 4);
      u32x4 o = { f2bf2(v0[0], v0[1]), f2bf2(v0[2], v0[3]),
                  f2bf2(v1[0], v1[1]), f2bf2(v1[2], v1[3]) };
      *reinterpret_cast<u32x4*>(As + row * 64 + ((ks ^ (row & 7)) << 3)) = o;
    }
    __syncthreads();
    // compute
#pragma unroll
    for (int kh = 0; kh < 2; kh++) {
      const int cp = (kh << 2) + kg;
      // dA B-fragments (L2-resident acatt): issue first so latency hides under ds_reads
      s16x8 bd[3];
#pragma unroll
      for (int nf = 0; nf < 3; nf++)
        bd[nf] = *reinterpret_cast<const s16x8*>(
            acatt + ((nf << 4) + lr) * 1024 + (kc << 6) + (kh << 5) + (kg << 3));
      s16x8 av[4], bv[4];
#pragma unroll
      for (int mf = 0; mf < 4; mf++) {
        int arow = (wr << 6) + (mf << 4) + lr;
        av[mf] = *reinterpret_cast<const s16x8*>(As + arow * 64 + ((cp ^ (arow & 7)) << 3));
      }
#pragma unroll
      for (int nf = 0; nf < 4; nf++) {
        int brow = (wc << 6) + (nf << 4) + lr;
        bv[nf] = *reinterpret_cast<const s16x8*>(Bs + brow * 64 + ((cp ^ (brow & 7)) << 3));
      }
#pragma unroll
      for (int mf = 0; mf < 4; mf++)
#pragma unroll
        for (int nf = 0; nf < 4; nf++)
          acc[mf][nf] = __builtin_amdgcn_mfma_f32_16x16x32_bf16(av[mf], bv[nf], acc[mf][nf], 0, 0, 0);
      // dA: rows w*32 + mf2*16
#pragma unroll
      for (int mf2 = 0; mf2 < 2; mf2++) {
        int arow2 = (w << 5) + (mf2 << 4) + lr;
        s16x8 av2 = *reinterpret_cast<const s16x8*>(As + arow2 * 64 + ((cp ^ (arow2 & 7)) << 3));
#pragma unroll
        for (int nf = 0; nf < 3; nf++)
          accd[mf2][nf] = __builtin_amdgcn_mfma_f32_16x16x32_bf16(av2, bd[nf], accd[mf2][nf], 0, 0, 0);
      }
    }
  }

  // ---- tail: dA -> LDS (overlaying As/Bs), attention per row, dom in LDS ----
  __syncthreads();
  float (*dAs)[41] = (float(*)[41])smem;                 // 128 x 41 f32 = 20992 B
  float (*domL)[4] = (float(*)[4])(smem + 20992);        // 128 x 4  f32 = 2048 B
#pragma unroll
  for (int mf2 = 0; mf2 < 2; mf2++)
#pragma unroll
    for (int nf = 0; nf < 3; nf++) {
      const int col = (nf << 4) + lr;
      if (col < 40) {
#pragma unroll
        for (int j = 0; j < 4; j++)
          dAs[(w << 5) + (mf2 << 4) + (kg << 2) + j][col] = accd[mf2][nf][j];
      }
    }
  __syncthreads();
  if (t < 128) {
    const int row = t;
    const float* Gp = ws_f + (WS_G >> 2);
    const float* Mp = ws_f + (WS_M >> 2);
    float Gv[16];
#pragma unroll
    for (int i = 0; i < 16; i++) Gv[i] = Gp[i];
    float tm[10][4];
#pragma unroll
    for (int m = 0; m < 10; m++) {
      float d0 = dAs[row][(m << 2) + 0], d1 = dAs[row][(m << 2) + 1];
      float d2 = dAs[row][(m << 2) + 2], d3 = dAs[row][(m << 2) + 3];
#pragma unroll
      for (int r = 0; r < 4; r++)
        tm[m][r] = Gv[(r << 2) + 0] * d0 + Gv[(r << 2) + 1] * d1
                 + Gv[(r << 2) + 2] * d2 + Gv[(r << 2) + 3] * d3;
    }
    float cm[10];
#pragma unroll
    for (int m = 0; m < 10; m++) cm[m] = 0.f;
#pragma unroll
    for (int n = 0; n < 10; n++) {
      float d0 = dAs[row][(n << 2) + 0], d1 = dAs[row][(n << 2) + 1];
      float d2 = dAs[row][(n << 2) + 2], d3 = dAs[row][(n << 2) + 3];
      float sv[10]; float mx = -1e30f;
#pragma unroll
      for (int m = 0; m < 10; m++) {
        float s = d0 * tm[m][0] + d1 * tm[m][1] + d2 * tm[m][2] + d3 * tm[m][3];
        sv[m] = s; mx = fmaxf(mx, s);
      }
      float ssum = 0.f;
#pragma unroll
      for (int m = 0; m < 10; m++) { float e = expf(sv[m] - mx); sv[m] = e; ssum += e; }
      float inv = 1.0f / ssum;
#pragma unroll
      for (int m = 0; m < 10; m++) cm[m] += sv[m] * inv;
    }
    float u0 = 0.f, u1 = 0.f, u2 = 0.f, u3 = 0.f;
#pragma unroll
    for (int m = 0; m < 10; m++) {
      u0 += cm[m] * dAs[row][(m << 2) + 0];
      u1 += cm[m] * dAs[row][(m << 2) + 1];
      u2 += cm[m] * dAs[row][(m << 2) + 2];
      u3 += cm[m] * dAs[row][(m << 2) + 3];
    }
#pragma unroll
    for (int rp = 0; rp < 4; rp++)
      domL[row][rp] = u0 * Mp[rp] + u1 * Mp[4 + rp] + u2 * Mp[8 + rp] + u3 * Mp[12 + rp];
  }
  __syncthreads();

  // ---- epilogue: + bias_tot + dom@Beff, relu ----
  float bcv[4], bev[4][4];
#pragma unroll
  for (int nf = 0; nf < 4; nf++) {
    int col = cols0 + (wc << 6) + (nf << 4) + lr;
    bcv[nf] = btot[col];
#pragma unroll
    for (int r = 0; r < 4; r++) bev[nf][r] = beff[r * 1024 + col];
  }
#pragma unroll
  for (int mf = 0; mf < 4; mf++) {
    const int lbase = (wr << 6) + (mf << 4) + (kg << 2);
    f32x4 dm[4];
#pragma unroll
    for (int j = 0; j < 4; j++)
      dm[j] = *reinterpret_cast<const f32x4*>(domL[lbase + j]);
#pragma unroll
    for (int nf = 0; nf < 4; nf++) {
      const int col = cols0 + (wc << 6) + (nf << 4) + lr;
#pragma unroll
      for (int j = 0; j < 4; j++) {
        float v = acc[mf][nf][j] + bcv[nf]
                + dm[j][0] * bev[nf][0] + dm[j][1] * bev[nf][1]
                + dm[j][2] * bev[nf][2] + dm[j][3] * bev[nf][3];
        out[(size_t)(rows0 + lbase + j) * 1024 + col] = fmaxf(v, 0.f);
      }
    }
  }
}

extern "C" void kernel_launch(void* const* d_in, const int* in_sizes, int n_in,
                              void* d_out, int out_size, void* d_ws, size_t ws_size,
                              hipStream_t stream) {
  (void)in_sizes; (void)n_in; (void)out_size; (void)ws_size;
  const float* x           = (const float*)d_in[0];
  const int*   dom_ind     = (const int*)d_in[1];
  const float* kern        = (const float*)d_in[2];
  const float* bias        = (const float*)d_in[3];
  const float* a_kernel    = (const float*)d_in[4];
  const float* b_kernel    = (const float*)d_in[5];
  const float* domain_bias = (const float*)d_in[6];
  const float* WQ          = (const float*)d_in[7];
  const float* WK          = (const float*)d_in[8];
  const float* WV          = (const float*)d_in[9];
  const float* linear      = (const float*)d_in[10];
  const float* factor      = (const float*)d_in[11];
  float* out = (float*)d_out;
  char* ws = (char*)d_ws;
  float* ws_f = (float*)ws;
  unsigned short* acatt = (unsigned short*)(ws + WS_ACATT);
  unsigned short* kb    = (unsigned short*)(ws + WS_KB);

  prep1<<<1, 256, 0, stream>>>(factor, WQ, WK, WV, linear, bias, domain_bias, b_kernel, dom_ind, ws_f);
  prep2<<<256, 256, 0, stream>>>(a_kernel, acatt);
  transK<<<1024, 256, 0, stream>>>(kern, kb);
  fusedGEMM<<<2048, 256, 0, stream>>>(x, kb, acatt, ws_f, out);
}